// Round 10
// baseline (2245.513 us; speedup 1.0000x reference)
//
#include <hip/hip_runtime.h>
#include <math.h>

#define NN 50000
#define EE 800000
#define HH 128
#define FF 64
#define GG 8
#define PB 500      // pool phase-1 blocks (covers 100 rows each)
#define SB 1600     // scatter blocks: 200 per dst-group, 8 groups

using short8 = __attribute__((ext_vector_type(8))) short;
using f32x4  = __attribute__((ext_vector_type(4))) float;
using f32x2  = __attribute__((ext_vector_type(2))) float;

__device__ __forceinline__ float sigm(float x){ return 1.0f/(1.0f+expf(-x)); }
__device__ __forceinline__ unsigned short f2bf(float f){
    union { float f; unsigned u; } v; v.f = f;
    unsigned r = v.u + 0x7fff + ((v.u >> 16) & 1);
    return (unsigned short)(r >> 16);
}
__device__ __forceinline__ float bf2f(unsigned short h){
    union { unsigned u; float f; } v; v.u = ((unsigned)h) << 16;
    return v.f;
}

// ---------- fp8 helpers (HW cvt on gfx950; self-consistent either format) ----------
#if __has_builtin(__builtin_amdgcn_cvt_pk_fp8_f32) && __has_builtin(__builtin_amdgcn_cvt_pk_f32_fp8)
#define FP8_HW 1
#else
#define FP8_HW 0
#endif

__device__ __forceinline__ unsigned fp8enc1_sw(float f){
    union { float fl; unsigned u; } x; x.fl = f;
    unsigned s = (x.u >> 31) << 7;
    float a = fabsf(f);
    if (!(a > 0.f)) return s;
    if (a >= 448.f) return s | 0x7E;
    if (a < 0.015625f) {
        int q = (int)(a * 512.f + 0.5f);
        if (q > 7) return s | (1u << 3);
        return s | (unsigned)q;
    }
    unsigned u = x.u + (1u << 19);          // round at 3-bit mantissa
    int e32 = (int)((u >> 23) & 255) - 127;
    if (e32 < -6) { int q=(int)(a*512.f+0.5f); if(q>7)q=7; return s|(unsigned)q; }
    if (e32 > 8) return s | 0x7E;
    unsigned m = (u >> 20) & 7;
    return s | ((unsigned)(e32 + 7) << 3) | m;
}
__device__ __forceinline__ float fp8dec1_sw(unsigned v){
    unsigned s = v >> 7, e = (v >> 3) & 15, m = v & 7;
    float f;
    if (e == 0) f = (float)m * 0.001953125f;
    else { union { unsigned u; float fl; } x; x.u = ((e + 120u) << 23) | (m << 20); f = x.fl; }
    return s ? -f : f;
}
__device__ __forceinline__ unsigned char e2fp8(float a){
#if FP8_HW
    return (unsigned char)(__builtin_amdgcn_cvt_pk_fp8_f32(a, a, 0, false) & 0xFF);
#else
    return (unsigned char)fp8enc1_sw(a);
#endif
}
__device__ __forceinline__ unsigned pk4fp8(float a, float b, float c, float d){
#if FP8_HW
    unsigned p0 = (unsigned)__builtin_amdgcn_cvt_pk_fp8_f32(a, b, 0, false);
    unsigned p1 = (unsigned)__builtin_amdgcn_cvt_pk_fp8_f32(c, d, 0, false);
    return (p0 & 0xFFFFu) | ((p1 & 0xFFFFu) << 16);
#else
    return fp8enc1_sw(a) | (fp8enc1_sw(b) << 8) | (fp8enc1_sw(c) << 16) | (fp8enc1_sw(d) << 24);
#endif
}
__device__ __forceinline__ float2 d2fp8(unsigned short u){
#if FP8_HW
    f32x2 r = __builtin_amdgcn_cvt_pk_f32_fp8((int)(unsigned)u, false);
    return make_float2(r[0], r[1]);
#else
    return make_float2(fp8dec1_sw(u & 0xFF), fp8dec1_sw((u >> 8) & 0xFF));
#endif
}

// ---------- setup (block 0) + graph bounds (block 1) ----------
__global__ void k_setup(const float* __restrict__ meth,
                        const float* __restrict__ histones,
                        const float* __restrict__ logd,
                        float* __restrict__ scal,
                        const int* __restrict__ batch, int* __restrict__ st)
{
    if (blockIdx.x == 1) {
        int g = threadIdx.x;
        if (g > GG) return;
        int lo = 0, hi = NN;
        while (lo < hi) { int mid = (lo + hi) >> 1; if (batch[mid] < g) lo = mid + 1; else hi = mid; }
        st[g] = lo;
        return;
    }
    int l = threadIdx.x;
    float s = sigm(meth[l]) + sigm(meth[l + 64]);
#pragma unroll
    for (int o = 32; o >= 1; o >>= 1) s += __shfl_xor(s, o, 64);
    if (l == 0) {
        float msil = s * (1.0f / 128.0f);
        float h0 = sigm(histones[0]), h1 = sigm(histones[1]);
        float h2 = sigm(histones[2]), h3 = sigm(histones[3]);
        float act = (h0 + h2) * 0.5f, rep = (h1 + h3) * 0.5f;
        float chrom = fminf(fmaxf(act - rep + 0.5f, 0.0f), 1.0f);
        scal[0] = chrom * (1.0f - msil);
        float d = expf(logd[0]);
        scal[1] = fminf(fmaxf(d, 0.1f), 3.0f);   // dt
    }
}

// ---------- single merged weight pack: all 7 matrices -> one contiguous bf16 buffer ----------
__global__ void k_packall(const float* __restrict__ in_w, const float* __restrict__ gcn_w,
                          const float* __restrict__ gate_w, const float* __restrict__ out_w,
                          unsigned short* __restrict__ outp)
{
    int i = blockIdx.x * 256 + threadIdx.x;
    if (i >= 8192 + 6 * 16384) return;
    const float* src; int base, li;
    if (i < 8192) { src = in_w + i; base = 0; li = i; }
    else {
        int j = i - 8192;
        int m = j >> 14, r = j & 16383;
        base = 8192 + (m << 14); li = r;
        if (m < 3)      src = gcn_w  + m * 16384 + r;
        else if (m < 5) src = gate_w + (m - 3) * 16384 + r;
        else            src = out_w + r;
    }
    int k = li >> 7, n = li & 127;
    int c = k >> 5, kl = k & 31, q = kl >> 3, j2 = kl & 7;
    int b = n >> 4, ln = n & 15;
    int lane = q * 16 + ln;
    outp[base + ((c * 8 + b) * 64 + lane) * 8 + j2] = f2bf(*src);
}

// ---------- x fp32 -> bf16 ----------
__global__ void k_cvtx(const float* __restrict__ x, unsigned short* __restrict__ xb)
{
    size_t i = (size_t)blockIdx.x * 256 + threadIdx.x;
    if (i >= (size_t)NN * 16) return;
    float4 v = ((const float4*)x)[i];
    ushort4 o;
    o.x = f2bf(v.x); o.y = f2bf(v.y); o.z = f2bf(v.z); o.w = f2bf(v.w);
    ((ushort4*)xb)[i] = o;
}

// ---------- CSR build ----------
__global__ void k_hist(const int* __restrict__ ei, int* __restrict__ hist)
{
    int e = blockIdx.x * 256 + threadIdx.x;
    if (e < EE) atomicAdd(&hist[ei[EE + e]], 1);
}

__global__ void k_dinv(const int* __restrict__ hist, float* __restrict__ dinv)
{
    int n = blockIdx.x * 256 + threadIdx.x;
    if (n < NN) {
        int d = hist[n];
        dinv[n] = d > 0 ? rsqrtf((float)d) : 0.0f;
    }
}

__global__ void k_scan_a(const int* __restrict__ hist, int* __restrict__ aux)
{
    __shared__ int sh[256];
    int b = blockIdx.x, t = threadIdx.x;
    int base = b * 1024 + t * 4;
    int s = 0;
#pragma unroll
    for (int j = 0; j < 4; ++j) { int i = base + j; if (i < NN) s += hist[i]; }
    sh[t] = s; __syncthreads();
    for (int o = 128; o >= 1; o >>= 1) { if (t < o) sh[t] += sh[t + o]; __syncthreads(); }
    if (t == 0) aux[b] = sh[0];
}

__global__ void k_scan_b(int* __restrict__ aux, int nb)
{
    if (blockIdx.x == 0 && threadIdx.x == 0) {
        int run = 0;
        for (int i = 0; i < nb; ++i) { int v = aux[i]; aux[i] = run; run += v; }
    }
}

__global__ void k_scan_c(const int* __restrict__ hist, const int* __restrict__ aux,
                         int* __restrict__ row_ptr)
{
    __shared__ int sh[256];
    int b = blockIdx.x, t = threadIdx.x;
    int base = b * 1024 + t * 4;
    int v[4]; int s = 0;
#pragma unroll
    for (int j = 0; j < 4; ++j) { int i = base + j; v[j] = (i < NN) ? hist[i] : 0; s += v[j]; }
    sh[t] = s; __syncthreads();
    for (int o = 1; o < 256; o <<= 1) {
        int x = 0; if (t >= o) x = sh[t - o];
        __syncthreads(); sh[t] += x; __syncthreads();
    }
    int run = aux[b] + sh[t] - s;
#pragma unroll
    for (int j = 0; j < 4; ++j) { int i = base + j; if (i < NN) row_ptr[i] = run; run += v[j]; }
    if (b == 0 && t == 0) row_ptr[NN] = EE;
}

// ---------- dst-partitioned scatter (group g handles dst slice g; ~1x write amp) ----------
// packed edge record: word0 = src(16b) | dloc(4b)<<16, word1 = fp32 weight bits
__global__ __launch_bounds__(256) void k_scatter(const int* __restrict__ ei,
                          const float* __restrict__ dinv,
                          int* __restrict__ cursor, uint2* __restrict__ ew)
{
    if (blockIdx.x == 0 && threadIdx.x < 128)    // tail pads for spgemm prefetch
        ew[EE + threadIdx.x] = make_uint2(0u, 0u);
    const int grp = blockIdx.x & 7;
    const int blk = blockIdx.x >> 3;             // 0..SB/8-1
    const int CH  = EE / (SB / 8);               // 4000
    const int e0 = blk * CH, e1 = e0 + CH;
    const int glo = grp * (NN / 8), ghi = glo + (NN / 8);
    for (int e = e0 + threadIdx.x; e < e1; e += 256) {
        int d = ei[EE + e];
        if (d >= glo && d < ghi) {
            int s = ei[e];
            int p = atomicAdd(&cursor[d], 1);
            ew[p] = make_uint2((unsigned)(s & 0xFFFF) | ((unsigned)(d & 15) << 16),
                               __float_as_uint(dinv[s] * dinv[d]));
        }
    }
}

// ---------- MFMA dense (LDS-staged W): out = [relu(]LN(A@W+b)[)*sc] (+fp8 shadow) ----------
template<int KC, int MODE>
__global__ __launch_bounds__(256) void k_dense_mfma(
    const unsigned short* __restrict__ A, const unsigned short* __restrict__ Wp,
    const float* __restrict__ bias, const float* __restrict__ lng,
    const float* __restrict__ lnb, const float* __restrict__ scal,
    unsigned short* __restrict__ out, unsigned char* __restrict__ out8)
{
    __shared__ unsigned short Ws[KC * 4096];
    const int t = threadIdx.x;
    {
        const float4* src = (const float4*)Wp;
        float4* dst = (float4*)Ws;
#pragma unroll
        for (int i = 0; i < KC * 2; ++i) dst[t + i * 256] = src[t + i * 256];
    }
    __syncthreads();
    const int wave = t >> 6, lane = t & 63;
    const int quad = lane >> 4, ln = lane & 15;
    const int r0 = blockIdx.x * 64 + wave * 16;
    const int K = KC * 32;
    const int arow = r0 + ln;
    const bool av = arow < NN;

    f32x4 acc[8] = {};
#pragma unroll
    for (int c = 0; c < KC; ++c) {
        short8 a = {};
        if (av) a = *(const short8*)(A + (size_t)arow * K + c * 32 + quad * 8);
#pragma unroll
        for (int b = 0; b < 8; ++b) {
            short8 bb = *(const short8*)&Ws[((c * 8 + b) * 64 + lane) * 8];
            acc[b] = __builtin_amdgcn_mfma_f32_16x16x32_bf16(a, bb, acc[b], 0, 0, 0);
        }
    }

    float b_s[8], g_s[8], e_s[8];
#pragma unroll
    for (int b = 0; b < 8; ++b) {
        int col = b * 16 + ln;
        b_s[b] = bias[col]; g_s[b] = lng[col]; e_s[b] = lnb[col];
    }
    float sc = (MODE == 1) ? scal[0] : 0.0f;
#pragma unroll
    for (int i = 0; i < 4; ++i) {
        int row = r0 + quad * 4 + i;
        float v[8]; float s = 0.f, q = 0.f;
#pragma unroll
        for (int b = 0; b < 8; ++b) { float x = acc[b][i] + b_s[b]; v[b] = x; s += x; q += x * x; }
#pragma unroll
        for (int o = 1; o < 16; o <<= 1) { s += __shfl_xor(s, o, 64); q += __shfl_xor(q, o, 64); }
        float m  = s * (1.0f / 128.0f);
        float vr = q * (1.0f / 128.0f) - m * m;
        float rs = rsqrtf(vr + 1e-5f);
        if (row < NN) {
#pragma unroll
            for (int b = 0; b < 8; ++b) {
                float o2 = (v[b] - m) * rs * g_s[b] + e_s[b];
                if (MODE == 1) o2 = fmaxf(o2, 0.f) * sc;
                out[(size_t)row * 128 + b * 16 + ln] = f2bf(o2);
                if (out8) out8[(size_t)row * 128 + b * 16 + ln] = e2fp8(o2);
            }
        }
    }
}

// ---------- fused SpMM + GEMM + LN (fp8 gather; 4 edge-subgroups x 16 lanes) ----------
// Wave owns 8 CSR-contiguous nodes. Lane = 16*sg + li: subgroup sg handles
// edges e+4j+sg; lane covers 8 fp8 columns (uint2 = full row per subgroup).
// 4x MLP + 4x shallower serial chain vs wave-per-edge. Per-subgroup run
// accumulators flushed with ds_add_f32 into pre-zeroed LDS rows (partials
// from different subgroups add commutatively; pads never consumed).
__global__ __launch_bounds__(128) void k_spgemm(
    const int* __restrict__ rp, const uint2* __restrict__ ew,
    const unsigned char* __restrict__ X8, const unsigned short* __restrict__ Wp,
    const float* __restrict__ bias, const float* __restrict__ lng,
    const float* __restrict__ lnb, unsigned short* __restrict__ out,
    unsigned char* __restrict__ out8)
{
    __shared__ float accf[16 * 132];          // 16 rows, stride 132 (pad 4)
    const int t = threadIdx.x, wave = t >> 6, lane = t & 63;
    const int quad = lane >> 4, ln = lane & 15;
    const int sg = quad, li = ln;
    const int n0 = blockIdx.x * 16;
    const int nf = n0 + wave * 8;

    // zero own rows (same-wave program order; no cross-wave writes in edge phase)
    {
        float* z = accf + wave * 8 * 132;
        for (int i = lane; i < 8 * 132; i += 64) z[i] = 0.f;
    }

    if (nf < NN) {
        const int nl = min(nf + 8, NN);
        const int ebeg = __builtin_amdgcn_readfirstlane(rp[nf]);
        const int eend = __builtin_amdgcn_readfirstlane(rp[nl]);
        if (ebeg < eend) {
            float acc8[8] = {};
            int curd = wave * 8;              // own first row: degenerate flushes stay local
            const unsigned char* Xl = X8 + li * 8;
            uint2 rec[8], recN[8], g[8];
#pragma unroll
            for (int j = 0; j < 8; ++j) rec[j]  = ew[ebeg + 4 * j + sg];        // pad-safe
#pragma unroll
            for (int j = 0; j < 8; ++j) recN[j] = ew[ebeg + 32 + 4 * j + sg];   // pad-safe
#pragma unroll
            for (int j = 0; j < 8; ++j) {
                int src = (int)(rec[j].x & 0xFFFFu);
                g[j] = *(const uint2*)(Xl + (size_t)src * 128);
            }
            for (int e = ebeg; e < eend; e += 32) {
                // issue next round's gathers + round-after-next records
                uint2 gN[8], recNN[8];
#pragma unroll
                for (int j = 0; j < 8; ++j) {
                    int src = (int)(recN[j].x & 0xFFFFu);
                    gN[j] = *(const uint2*)(Xl + (size_t)src * 128);
                }
#pragma unroll
                for (int j = 0; j < 8; ++j) recNN[j] = ew[e + 64 + 4 * j + sg]; // pad-safe
                // consume current round (waits only on g)
                int lim = eend - e - sg;                 // valid j: 4j < lim
                int mj = lim > 0 ? ((lim + 3) >> 2) : 0; if (mj > 8) mj = 8;
#pragma unroll
                for (int j = 0; j < 8; ++j) {
                    if (j >= mj) break;                  // subgroup-uniform
                    float wgt = __uint_as_float(rec[j].y);
                    int dl = (int)((rec[j].x >> 16) & 15u);
                    if (dl != curd) {                    // subgroup-uniform (exec-masked)
                        float* row = accf + curd * 132 + li * 8;
#pragma unroll
                        for (int k = 0; k < 8; ++k) { atomicAdd(&row[k], acc8[k]); acc8[k] = 0.f; }
                        curd = dl;
                    }
                    float2 p0 = d2fp8((unsigned short)(g[j].x & 0xFFFFu));
                    float2 p1 = d2fp8((unsigned short)(g[j].x >> 16));
                    float2 p2 = d2fp8((unsigned short)(g[j].y & 0xFFFFu));
                    float2 p3 = d2fp8((unsigned short)(g[j].y >> 16));
                    acc8[0] = fmaf(wgt, p0.x, acc8[0]); acc8[1] = fmaf(wgt, p0.y, acc8[1]);
                    acc8[2] = fmaf(wgt, p1.x, acc8[2]); acc8[3] = fmaf(wgt, p1.y, acc8[3]);
                    acc8[4] = fmaf(wgt, p2.x, acc8[4]); acc8[5] = fmaf(wgt, p2.y, acc8[5]);
                    acc8[6] = fmaf(wgt, p3.x, acc8[6]); acc8[7] = fmaf(wgt, p3.y, acc8[7]);
                }
#pragma unroll
                for (int j = 0; j < 8; ++j) { rec[j] = recN[j]; recN[j] = recNN[j]; g[j] = gN[j]; }
            }
            {   // final flush
                float* row = accf + curd * 132 + li * 8;
#pragma unroll
                for (int k = 0; k < 8; ++k) atomicAdd(&row[k], acc8[k]);
            }
        }
    }
    __syncthreads();

    // MFMA phase (redundant across the 2 waves): A-frags from LDS, B from L2
    f32x4 acc[8] = {};
    const float* ar = accf + (size_t)ln * 132;
#pragma unroll
    for (int c = 0; c < 4; ++c) {
        float4 a0 = *(const float4*)(ar + c * 32 + quad * 8);
        float4 a1 = *(const float4*)(ar + c * 32 + quad * 8 + 4);
        short8 af;
        af[0] = (short)f2bf(a0.x); af[1] = (short)f2bf(a0.y);
        af[2] = (short)f2bf(a0.z); af[3] = (short)f2bf(a0.w);
        af[4] = (short)f2bf(a1.x); af[5] = (short)f2bf(a1.y);
        af[6] = (short)f2bf(a1.z); af[7] = (short)f2bf(a1.w);
#pragma unroll
        for (int b = 0; b < 8; ++b) {
            short8 bb = *(const short8*)(Wp + ((size_t)(c * 8 + b) * 64 + lane) * 8);
            acc[b] = __builtin_amdgcn_mfma_f32_16x16x32_bf16(af, bb, acc[b], 0, 0, 0);
        }
    }

    float b_s[8], g_s[8], e_s[8];
#pragma unroll
    for (int b = 0; b < 8; ++b) {
        int col = b * 16 + ln;
        b_s[b] = bias[col]; g_s[b] = lng[col]; e_s[b] = lnb[col];
    }
#pragma unroll
    for (int i = 0; i < 4; ++i) {
        int row = n0 + quad * 4 + i;
        float v[8]; float s = 0.f, q = 0.f;
#pragma unroll
        for (int b = 0; b < 8; ++b) { float x = acc[b][i] + b_s[b]; v[b] = x; s += x; q += x * x; }
#pragma unroll
        for (int o = 1; o < 16; o <<= 1) { s += __shfl_xor(s, o, 64); q += __shfl_xor(q, o, 64); }
        float m  = s * (1.0f / 128.0f);
        float vr = q * (1.0f / 128.0f) - m * m;
        float rs = rsqrtf(vr + 1e-5f);
        if (((quad >> 1) == wave) && row < NN) {   // each wave stores its half
#pragma unroll
            for (int b = 0; b < 8; ++b) {
                float o2 = (v[b] - m) * rs * g_s[b] + e_s[b];
                out[(size_t)row * 128 + b * 16 + ln] = f2bf(o2);
                if (out8) out8[(size_t)row * 128 + b * 16 + ln] = e2fp8(o2);
            }
        }
    }
}

// ---------- MFMA gate (LDS-staged W), writes bf16 + fp8 shadow ----------
__global__ __launch_bounds__(256) void k_gate_mfma(
    unsigned short* __restrict__ cur, const unsigned short* __restrict__ hnew,
    const unsigned short* __restrict__ Wp, const float* __restrict__ gb,
    unsigned char* __restrict__ cur8)
{
    __shared__ unsigned short Ws[16384];
    const int t = threadIdx.x;
    const int wave = t >> 6, lane = t & 63;
    const int quad = lane >> 4, ln = lane & 15;
    const int r0 = blockIdx.x * 64 + wave * 16;
    const int arow = r0 + ln;
    const bool av = arow < NN;

    f32x4 acc[8] = {};
#pragma unroll
    for (int s = 0; s < 2; ++s) {
        __syncthreads();
        {
            const float4* src = (const float4*)(Wp + (size_t)s * 16384);
            float4* dst = (float4*)Ws;
#pragma unroll
            for (int i = 0; i < 8; ++i) dst[t + i * 256] = src[t + i * 256];
        }
        __syncthreads();
        const unsigned short* A = s ? hnew : cur;
#pragma unroll
        for (int c = 0; c < 4; ++c) {
            short8 a = {};
            if (av) a = *(const short8*)(A + (size_t)arow * 128 + c * 32 + quad * 8);
#pragma unroll
            for (int b = 0; b < 8; ++b) {
                short8 bb = *(const short8*)&Ws[((c * 8 + b) * 64 + lane) * 8];
                acc[b] = __builtin_amdgcn_mfma_f32_16x16x32_bf16(a, bb, acc[b], 0, 0, 0);
            }
        }
    }

    float gb_s[8];
#pragma unroll
    for (int b = 0; b < 8; ++b) gb_s[b] = gb[b * 16 + ln];
#pragma unroll
    for (int i = 0; i < 4; ++i) {
        int row = r0 + quad * 4 + i;
        if (row < NN) {
#pragma unroll
            for (int b = 0; b < 8; ++b) {
                size_t idx = (size_t)row * 128 + b * 16 + ln;
                float g  = sigm(acc[b][i] + gb_s[b]);
                float cu = bf2f(cur[idx]);
                float hn = bf2f(hnew[idx]);
                float r  = g * hn + (1.f - g) * cu;
                cur[idx]  = f2bf(r);
                cur8[idx] = e2fp8(r);
            }
        }
    }
}

// ---------- RK4 stage combine (bf16 state, fp32 accumulator, fp8 shadow of y) ----------
template<int S>
__global__ __launch_bounds__(256) void k_stage(
    const unsigned short* __restrict__ cur, const unsigned short* __restrict__ fin,
    const unsigned short* __restrict__ h0, float* __restrict__ acc,
    unsigned short* __restrict__ ybuf, const float* __restrict__ scal,
    const float* __restrict__ rwp, unsigned char* __restrict__ y8)
{
    size_t i = (size_t)blockIdx.x * 256 + threadIdx.x;
    if (i >= (size_t)NN * 32) return;
    float dt = scal[1], rw = rwp[0];
    float wk = (S == 1 || S == 4) ? dt * (1.f / 6.f) : dt * (1.f / 3.f);
    ushort4 c4 = ((const ushort4*)cur)[i];
    ushort4 f4 = ((const ushort4*)fin)[i];
    ushort4 h4 = ((const ushort4*)h0)[i];
    float tv[4];
    tv[0] = tanhf(bf2f(c4.x)) + rw * bf2f(f4.x);
    tv[1] = tanhf(bf2f(c4.y)) + rw * bf2f(f4.y);
    tv[2] = tanhf(bf2f(c4.z)) + rw * bf2f(f4.z);
    tv[3] = tanhf(bf2f(c4.w)) + rw * bf2f(f4.w);
    float4 a;
    if (S == 1) { a.x = wk*tv[0]; a.y = wk*tv[1]; a.z = wk*tv[2]; a.w = wk*tv[3]; }
    else {
        a = ((const float4*)acc)[i];
        a.x += wk*tv[0]; a.y += wk*tv[1]; a.z += wk*tv[2]; a.w += wk*tv[3];
    }
    ((float4*)acc)[i] = a;
    float h[4] = { bf2f(h4.x), bf2f(h4.y), bf2f(h4.z), bf2f(h4.w) };
    float yv[4];
    if (S == 4) {
        yv[0] = h[0] + a.x; yv[1] = h[1] + a.y; yv[2] = h[2] + a.z; yv[3] = h[3] + a.w;
    } else {
        float cn = (S == 3) ? dt : 0.5f * dt;
        yv[0] = h[0] + cn*tv[0]; yv[1] = h[1] + cn*tv[1];
        yv[2] = h[2] + cn*tv[2]; yv[3] = h[3] + cn*tv[3];
    }
    ushort4 y;
    y.x = f2bf(yv[0]); y.y = f2bf(yv[1]); y.z = f2bf(yv[2]); y.w = f2bf(yv[3]);
    ((ushort4*)ybuf)[i] = y;
    ((unsigned*)y8)[i] = pk4fp8(yv[0], yv[1], yv[2], yv[3]);
}

// ---------- pooling, two-phase (pool1 writes all 8 groups -> no memset needed) ----------
__global__ __launch_bounds__(128) void k_pool1(
    const unsigned short* __restrict__ h, const int* __restrict__ batch,
    float* __restrict__ partial)
{
    int c = threadIdx.x, b = blockIdx.x;
    int r0 = b * (NN / PB), r1 = r0 + (NN / PB);
    float acc = 0.f;
    int gfirst = batch[r0], g = gfirst;
#pragma unroll 4
    for (int r = r0; r < r1; ++r) {
        int gg = batch[r];
        if (gg != g) {
            partial[(size_t)b * 1024 + g * 128 + c] = acc;
            for (int z = g + 1; z < gg; ++z) partial[(size_t)b * 1024 + z * 128 + c] = 0.f;
            acc = 0.f; g = gg;
        }
        acc += bf2f(h[(size_t)r * 128 + c]);
    }
    partial[(size_t)b * 1024 + g * 128 + c] = acc;
    for (int z = 0; z < gfirst; ++z)  partial[(size_t)b * 1024 + z * 128 + c] = 0.f;
    for (int z = g + 1; z < GG; ++z)  partial[(size_t)b * 1024 + z * 128 + c] = 0.f;
}

__global__ __launch_bounds__(256) void k_pool2(
    const float* __restrict__ partial, const int* __restrict__ st,
    float* __restrict__ out)
{
    __shared__ float sh[8][32];
    int cb = blockIdx.x & 3, g = blockIdx.x >> 2;
    int cl = threadIdx.x & 31, sl = threadIdx.x >> 5;
    int c = cb * 32 + cl;
    float s = 0.f;
    for (int b = sl; b < PB; b += 8) s += partial[(size_t)b * 1024 + g * 128 + c];
    sh[sl][cl] = s; __syncthreads();
    if (sl == 0) {
        float tt = 0.f;
#pragma unroll
        for (int i = 0; i < 8; ++i) tt += sh[i][cl];
        int cnt = st[g + 1] - st[g];
        out[g * 128 + c] = tt / (float)(cnt > 0 ? cnt : 1);
    }
}

// ---------- host ----------
static inline size_t al(size_t x) { return (x + 255) & ~(size_t)255; }

extern "C" void kernel_launch(void* const* d_in, const int* in_sizes, int n_in,
                              void* d_out, int out_size, void* d_ws, size_t ws_size,
                              hipStream_t stream)
{
    const float* x       = (const float*)d_in[0];
    const int*   ei      = (const int*)d_in[1];
    const int*   batch   = (const int*)d_in[2];
    const float* in_w    = (const float*)d_in[3];
    const float* in_b    = (const float*)d_in[4];
    const float* in_lng  = (const float*)d_in[5];
    const float* in_lnb  = (const float*)d_in[6];
    const float* meth    = (const float*)d_in[7];
    const float* histn   = (const float*)d_in[8];
    const float* logd    = (const float*)d_in[9];
    const float* gcn_w   = (const float*)d_in[10];
    const float* gcn_b   = (const float*)d_in[11];
    const float* ln_g    = (const float*)d_in[12];
    const float* ln_b    = (const float*)d_in[13];
    const float* gate_w  = (const float*)d_in[14];
    const float* gate_b  = (const float*)d_in[15];
    const float* rw      = (const float*)d_in[16];
    const float* out_w   = (const float*)d_in[17];
    const float* out_b   = (const float*)d_in[18];
    const float* out_lng = (const float*)d_in[19];
    const float* out_lnb = (const float*)d_in[20];
    float* out = (float*)d_out;

    char* w = (char*)d_ws;
    size_t off = 0;
    float* scal   = (float*)(w + off); off += al(16 * 4);
    int*   hist   = (int*)(w + off);   off += al((size_t)NN * 4);
    int*   rp     = (int*)(w + off);   off += al((size_t)(NN + 1) * 4);
    int*   cursor = (int*)(w + off);   off += al((size_t)(NN + 1) * 4);
    int*   aux    = (int*)(w + off);   off += al(64 * 4);
    int*   st     = (int*)(w + off);   off += al(16 * 4);
    float* dinv   = (float*)(w + off); off += al((size_t)NN * 4);
    uint2* ew     = (uint2*)(w + off); off += al((size_t)(EE + 128) * 8);
    float* partial= (float*)(w + off); off += al((size_t)PB * 1024 * 4);
    // packed bf16 weights: [in | gcn0 | gcn1 | gcn2 | gate0 | gate1 | out] contiguous
    unsigned short* wpak = (unsigned short*)(w + off); off += al((size_t)(8192 + 6 * 16384) * 2);
    unsigned short* inwp  = wpak;
    unsigned short* gcnwp = wpak + 8192;
    unsigned short* gwp   = wpak + 8192 + 3 * 16384;
    unsigned short* owp   = wpak + 8192 + 5 * 16384;
    // bf16 activations
    size_t B16 = al((size_t)NN * 128 * 2);
    unsigned short* xb  = (unsigned short*)(w + off); off += al((size_t)NN * 64 * 2);
    unsigned short* h0  = (unsigned short*)(w + off); off += B16;
    unsigned short* y   = (unsigned short*)(w + off); off += B16;
    unsigned short* cur = (unsigned short*)(w + off); off += B16;
    unsigned short* t2  = (unsigned short*)(w + off); off += B16;
    float* acc = (float*)(w + off); off += al((size_t)NN * 128 * 4);
    // fp8 gather shadows
    size_t B8 = al((size_t)NN * 128);
    unsigned char* h08  = (unsigned char*)(w + off); off += B8;
    unsigned char* y8   = (unsigned char*)(w + off); off += B8;
    unsigned char* cur8 = (unsigned char*)(w + off); off += B8;
    if (off > ws_size) return;

    hipMemsetAsync(hist, 0, (size_t)NN * 4, stream);

    // setup+bounds, merged pack, x conversion (independent)
    k_setup<<<2, 64, 0, stream>>>(meth, histn, logd, scal, batch, st);
    k_packall<<<(8192 + 6 * 16384 + 255) / 256, 256, 0, stream>>>(in_w, gcn_w, gate_w, out_w, wpak);
    k_cvtx<<<3125, 256, 0, stream>>>(x, xb);

    // CSR build
    k_hist<<<(EE + 255) / 256, 256, 0, stream>>>(ei, hist);
    k_dinv<<<(NN + 255) / 256, 256, 0, stream>>>(hist, dinv);
    k_scan_a<<<49, 256, 0, stream>>>(hist, aux);
    k_scan_b<<<1, 1, 0, stream>>>(aux, 49);
    k_scan_c<<<49, 256, 0, stream>>>(hist, aux, rp);
    hipMemcpyAsync(cursor, rp, (size_t)(NN + 1) * 4, hipMemcpyDeviceToDevice, stream);
    k_scatter<<<SB, 256, 0, stream>>>(ei, dinv, cursor, ew);

    const int DG = (NN + 63) / 64;     // 782 blocks (dense/gate)
    const int SG = (NN + 15) / 16;     // 3125 blocks (spgemm)
    k_dense_mfma<2, 1><<<DG, 256, 0, stream>>>(xb, inwp, in_b, in_lng, in_lnb, scal, h0, h08);

    for (int s = 1; s <= 4; ++s) {
        const unsigned short* fin = (s == 1) ? h0 : y;
        const unsigned char*  fin8 = (s == 1) ? h08 : y8;
        k_spgemm<<<SG, 128, 0, stream>>>(rp, ew, fin8, gcnwp, gcn_b, ln_g, ln_b, cur, cur8);
        for (int i = 1; i <= 2; ++i) {
            k_spgemm<<<SG, 128, 0, stream>>>(rp, ew, cur8,
                                             gcnwp + (size_t)i * 128 * 128, gcn_b + i * 128,
                                             ln_g + i * 128, ln_b + i * 128, t2, (unsigned char*)0);
            k_gate_mfma<<<DG, 256, 0, stream>>>(cur, t2, gwp, gate_b, cur8);
        }
        if (s == 1)      k_stage<1><<<6250, 256, 0, stream>>>(cur, fin, h0, acc, y, scal, rw, y8);
        else if (s == 2) k_stage<2><<<6250, 256, 0, stream>>>(cur, fin, h0, acc, y, scal, rw, y8);
        else if (s == 3) k_stage<3><<<6250, 256, 0, stream>>>(cur, fin, h0, acc, y, scal, rw, y8);
        else             k_stage<4><<<6250, 256, 0, stream>>>(cur, fin, h0, acc, y, scal, rw, y8);
    }

    // output projection + pool
    k_dense_mfma<4, 0><<<DG, 256, 0, stream>>>(y, owp, out_b, out_lng, out_lnb, scal, t2, (unsigned char*)0);
    k_pool1<<<PB, 128, 0, stream>>>(t2, batch, partial);
    k_pool2<<<GG * 4, 256, 0, stream>>>(partial, st, out);
}

// Round 11
// 897.497 us; speedup vs baseline: 2.5020x; 2.5020x over previous
//
#include <hip/hip_runtime.h>
#include <math.h>

#define NN 50000
#define EE 800000
#define HH 128
#define FF 64
#define GG 8
#define PB 500      // pool phase-1 blocks (covers 100 rows each)
#define SB 1600     // scatter blocks: 200 per dst-group, 8 groups

using short8 = __attribute__((ext_vector_type(8))) short;
using f32x4  = __attribute__((ext_vector_type(4))) float;
using f32x2  = __attribute__((ext_vector_type(2))) float;

__device__ __forceinline__ float sigm(float x){ return 1.0f/(1.0f+expf(-x)); }
__device__ __forceinline__ unsigned short f2bf(float f){
    union { float f; unsigned u; } v; v.f = f;
    unsigned r = v.u + 0x7fff + ((v.u >> 16) & 1);
    return (unsigned short)(r >> 16);
}
__device__ __forceinline__ float bf2f(unsigned short h){
    union { unsigned u; float f; } v; v.u = ((unsigned)h) << 16;
    return v.f;
}

// ---------- fp8 helpers (HW cvt on gfx950; self-consistent either format) ----------
#if __has_builtin(__builtin_amdgcn_cvt_pk_fp8_f32) && __has_builtin(__builtin_amdgcn_cvt_pk_f32_fp8)
#define FP8_HW 1
#else
#define FP8_HW 0
#endif

__device__ __forceinline__ unsigned fp8enc1_sw(float f){
    union { float fl; unsigned u; } x; x.fl = f;
    unsigned s = (x.u >> 31) << 7;
    float a = fabsf(f);
    if (!(a > 0.f)) return s;
    if (a >= 448.f) return s | 0x7E;
    if (a < 0.015625f) {
        int q = (int)(a * 512.f + 0.5f);
        if (q > 7) return s | (1u << 3);
        return s | (unsigned)q;
    }
    unsigned u = x.u + (1u << 19);          // round at 3-bit mantissa
    int e32 = (int)((u >> 23) & 255) - 127;
    if (e32 < -6) { int q=(int)(a*512.f+0.5f); if(q>7)q=7; return s|(unsigned)q; }
    if (e32 > 8) return s | 0x7E;
    unsigned m = (u >> 20) & 7;
    return s | ((unsigned)(e32 + 7) << 3) | m;
}
__device__ __forceinline__ float fp8dec1_sw(unsigned v){
    unsigned s = v >> 7, e = (v >> 3) & 15, m = v & 7;
    float f;
    if (e == 0) f = (float)m * 0.001953125f;
    else { union { unsigned u; float fl; } x; x.u = ((e + 120u) << 23) | (m << 20); f = x.fl; }
    return s ? -f : f;
}
__device__ __forceinline__ unsigned char e2fp8(float a){
#if FP8_HW
    return (unsigned char)(__builtin_amdgcn_cvt_pk_fp8_f32(a, a, 0, false) & 0xFF);
#else
    return (unsigned char)fp8enc1_sw(a);
#endif
}
__device__ __forceinline__ unsigned pk4fp8(float a, float b, float c, float d){
#if FP8_HW
    unsigned p0 = (unsigned)__builtin_amdgcn_cvt_pk_fp8_f32(a, b, 0, false);
    unsigned p1 = (unsigned)__builtin_amdgcn_cvt_pk_fp8_f32(c, d, 0, false);
    return (p0 & 0xFFFFu) | ((p1 & 0xFFFFu) << 16);
#else
    return fp8enc1_sw(a) | (fp8enc1_sw(b) << 8) | (fp8enc1_sw(c) << 16) | (fp8enc1_sw(d) << 24);
#endif
}
__device__ __forceinline__ float2 d2fp8(unsigned short u){
#if FP8_HW
    f32x2 r = __builtin_amdgcn_cvt_pk_f32_fp8((int)(unsigned)u, false);
    return make_float2(r[0], r[1]);
#else
    return make_float2(fp8dec1_sw(u & 0xFF), fp8dec1_sw((u >> 8) & 0xFF));
#endif
}

// ---------- setup (block 0) + graph bounds (block 1) ----------
__global__ void k_setup(const float* __restrict__ meth,
                        const float* __restrict__ histones,
                        const float* __restrict__ logd,
                        float* __restrict__ scal,
                        const int* __restrict__ batch, int* __restrict__ st)
{
    if (blockIdx.x == 1) {
        int g = threadIdx.x;
        if (g > GG) return;
        int lo = 0, hi = NN;
        while (lo < hi) { int mid = (lo + hi) >> 1; if (batch[mid] < g) lo = mid + 1; else hi = mid; }
        st[g] = lo;
        return;
    }
    int l = threadIdx.x;
    float s = sigm(meth[l]) + sigm(meth[l + 64]);
#pragma unroll
    for (int o = 32; o >= 1; o >>= 1) s += __shfl_xor(s, o, 64);
    if (l == 0) {
        float msil = s * (1.0f / 128.0f);
        float h0 = sigm(histones[0]), h1 = sigm(histones[1]);
        float h2 = sigm(histones[2]), h3 = sigm(histones[3]);
        float act = (h0 + h2) * 0.5f, rep = (h1 + h3) * 0.5f;
        float chrom = fminf(fmaxf(act - rep + 0.5f, 0.0f), 1.0f);
        scal[0] = chrom * (1.0f - msil);
        float d = expf(logd[0]);
        scal[1] = fminf(fmaxf(d, 0.1f), 3.0f);   // dt
    }
}

// ---------- single merged weight pack: all 7 matrices -> one contiguous bf16 buffer ----------
__global__ void k_packall(const float* __restrict__ in_w, const float* __restrict__ gcn_w,
                          const float* __restrict__ gate_w, const float* __restrict__ out_w,
                          unsigned short* __restrict__ outp)
{
    int i = blockIdx.x * 256 + threadIdx.x;
    if (i >= 8192 + 6 * 16384) return;
    const float* src; int base, li;
    if (i < 8192) { src = in_w + i; base = 0; li = i; }
    else {
        int j = i - 8192;
        int m = j >> 14, r = j & 16383;
        base = 8192 + (m << 14); li = r;
        if (m < 3)      src = gcn_w  + m * 16384 + r;
        else if (m < 5) src = gate_w + (m - 3) * 16384 + r;
        else            src = out_w + r;
    }
    int k = li >> 7, n = li & 127;
    int c = k >> 5, kl = k & 31, q = kl >> 3, j2 = kl & 7;
    int b = n >> 4, ln = n & 15;
    int lane = q * 16 + ln;
    outp[base + ((c * 8 + b) * 64 + lane) * 8 + j2] = f2bf(*src);
}

// ---------- x fp32 -> bf16 ----------
__global__ void k_cvtx(const float* __restrict__ x, unsigned short* __restrict__ xb)
{
    size_t i = (size_t)blockIdx.x * 256 + threadIdx.x;
    if (i >= (size_t)NN * 16) return;
    float4 v = ((const float4*)x)[i];
    ushort4 o;
    o.x = f2bf(v.x); o.y = f2bf(v.y); o.z = f2bf(v.z); o.w = f2bf(v.w);
    ((ushort4*)xb)[i] = o;
}

// ---------- CSR build ----------
__global__ void k_hist(const int* __restrict__ ei, int* __restrict__ hist)
{
    int e = blockIdx.x * 256 + threadIdx.x;
    if (e < EE) atomicAdd(&hist[ei[EE + e]], 1);
}

__global__ void k_dinv(const int* __restrict__ hist, float* __restrict__ dinv)
{
    int n = blockIdx.x * 256 + threadIdx.x;
    if (n < NN) {
        int d = hist[n];
        dinv[n] = d > 0 ? rsqrtf((float)d) : 0.0f;
    }
}

__global__ void k_scan_a(const int* __restrict__ hist, int* __restrict__ aux)
{
    __shared__ int sh[256];
    int b = blockIdx.x, t = threadIdx.x;
    int base = b * 1024 + t * 4;
    int s = 0;
#pragma unroll
    for (int j = 0; j < 4; ++j) { int i = base + j; if (i < NN) s += hist[i]; }
    sh[t] = s; __syncthreads();
    for (int o = 128; o >= 1; o >>= 1) { if (t < o) sh[t] += sh[t + o]; __syncthreads(); }
    if (t == 0) aux[b] = sh[0];
}

__global__ void k_scan_b(int* __restrict__ aux, int nb)
{
    if (blockIdx.x == 0 && threadIdx.x == 0) {
        int run = 0;
        for (int i = 0; i < nb; ++i) { int v = aux[i]; aux[i] = run; run += v; }
    }
}

__global__ void k_scan_c(const int* __restrict__ hist, const int* __restrict__ aux,
                         int* __restrict__ row_ptr)
{
    __shared__ int sh[256];
    int b = blockIdx.x, t = threadIdx.x;
    int base = b * 1024 + t * 4;
    int v[4]; int s = 0;
#pragma unroll
    for (int j = 0; j < 4; ++j) { int i = base + j; v[j] = (i < NN) ? hist[i] : 0; s += v[j]; }
    sh[t] = s; __syncthreads();
    for (int o = 1; o < 256; o <<= 1) {
        int x = 0; if (t >= o) x = sh[t - o];
        __syncthreads(); sh[t] += x; __syncthreads();
    }
    int run = aux[b] + sh[t] - s;
#pragma unroll
    for (int j = 0; j < 4; ++j) { int i = base + j; if (i < NN) row_ptr[i] = run; run += v[j]; }
    if (b == 0 && t == 0) row_ptr[NN] = EE;
}

// ---------- dst-partitioned scatter (group g handles dst slice g; ~1x write amp) ----------
// packed edge record: word0 = src(16b) | dloc(4b)<<16, word1 = fp32 weight bits
__global__ __launch_bounds__(256) void k_scatter(const int* __restrict__ ei,
                          const float* __restrict__ dinv,
                          int* __restrict__ cursor, uint2* __restrict__ ew)
{
    if (blockIdx.x == 0 && threadIdx.x < 128)    // tail pads for spgemm prefetch
        ew[EE + threadIdx.x] = make_uint2(0u, 0u);
    const int grp = blockIdx.x & 7;
    const int blk = blockIdx.x >> 3;             // 0..SB/8-1
    const int CH  = EE / (SB / 8);               // 4000
    const int e0 = blk * CH, e1 = e0 + CH;
    const int glo = grp * (NN / 8), ghi = glo + (NN / 8);
    for (int e = e0 + threadIdx.x; e < e1; e += 256) {
        int d = ei[EE + e];
        if (d >= glo && d < ghi) {
            int s = ei[e];
            int p = atomicAdd(&cursor[d], 1);
            ew[p] = make_uint2((unsigned)(s & 0xFFFF) | ((unsigned)(d & 15) << 16),
                               __float_as_uint(dinv[s] * dinv[d]));
        }
    }
}

// ---------- MFMA dense (LDS-staged W): out = [relu(]LN(A@W+b)[)*sc] (+fp8 shadow) ----------
template<int KC, int MODE>
__global__ __launch_bounds__(256) void k_dense_mfma(
    const unsigned short* __restrict__ A, const unsigned short* __restrict__ Wp,
    const float* __restrict__ bias, const float* __restrict__ lng,
    const float* __restrict__ lnb, const float* __restrict__ scal,
    unsigned short* __restrict__ out, unsigned char* __restrict__ out8)
{
    __shared__ unsigned short Ws[KC * 4096];
    const int t = threadIdx.x;
    {
        const float4* src = (const float4*)Wp;
        float4* dst = (float4*)Ws;
#pragma unroll
        for (int i = 0; i < KC * 2; ++i) dst[t + i * 256] = src[t + i * 256];
    }
    __syncthreads();
    const int wave = t >> 6, lane = t & 63;
    const int quad = lane >> 4, ln = lane & 15;
    const int r0 = blockIdx.x * 64 + wave * 16;
    const int K = KC * 32;
    const int arow = r0 + ln;
    const bool av = arow < NN;

    f32x4 acc[8] = {};
#pragma unroll
    for (int c = 0; c < KC; ++c) {
        short8 a = {};
        if (av) a = *(const short8*)(A + (size_t)arow * K + c * 32 + quad * 8);
#pragma unroll
        for (int b = 0; b < 8; ++b) {
            short8 bb = *(const short8*)&Ws[((c * 8 + b) * 64 + lane) * 8];
            acc[b] = __builtin_amdgcn_mfma_f32_16x16x32_bf16(a, bb, acc[b], 0, 0, 0);
        }
    }

    float b_s[8], g_s[8], e_s[8];
#pragma unroll
    for (int b = 0; b < 8; ++b) {
        int col = b * 16 + ln;
        b_s[b] = bias[col]; g_s[b] = lng[col]; e_s[b] = lnb[col];
    }
    float sc = (MODE == 1) ? scal[0] : 0.0f;
#pragma unroll
    for (int i = 0; i < 4; ++i) {
        int row = r0 + quad * 4 + i;
        float v[8]; float s = 0.f, q = 0.f;
#pragma unroll
        for (int b = 0; b < 8; ++b) { float x = acc[b][i] + b_s[b]; v[b] = x; s += x; q += x * x; }
#pragma unroll
        for (int o = 1; o < 16; o <<= 1) { s += __shfl_xor(s, o, 64); q += __shfl_xor(q, o, 64); }
        float m  = s * (1.0f / 128.0f);
        float vr = q * (1.0f / 128.0f) - m * m;
        float rs = rsqrtf(vr + 1e-5f);
        if (row < NN) {
#pragma unroll
            for (int b = 0; b < 8; ++b) {
                float o2 = (v[b] - m) * rs * g_s[b] + e_s[b];
                if (MODE == 1) o2 = fmaxf(o2, 0.f) * sc;
                out[(size_t)row * 128 + b * 16 + ln] = f2bf(o2);
                if (out8) out8[(size_t)row * 128 + b * 16 + ln] = e2fp8(o2);
            }
        }
    }
}

// ---------- fused SpMM + GEMM + LN (fp8 gather; 2 half-wave edge tracks) ----------
// Wave owns 8 CSR-contiguous nodes. Half h = lane>>5 processes edges e+2j+h;
// lane covers 4 fp8 cols (uint = 32 lanes x 4B = full 128B row per half).
// Each half flushes its float4 run-accumulator with a PLAIN store into its
// OWN buffer accf[h] (within a half, dsts form a nondecreasing subsequence ->
// each row stored once; no atomics, no cross-half race). MFMA phase reads
// accf[0]+accf[1]. 2x MLP, half the serial fma chain vs wave-per-edge.
__global__ __launch_bounds__(128) void k_spgemm(
    const int* __restrict__ rp, const uint2* __restrict__ ew,
    const unsigned char* __restrict__ X8, const unsigned short* __restrict__ Wp,
    const float* __restrict__ bias, const float* __restrict__ lng,
    const float* __restrict__ lnb, unsigned short* __restrict__ out,
    unsigned char* __restrict__ out8)
{
    __shared__ float accf[2][16 * 132];       // per-half buffers (16.9 KB)
    const int t = threadIdx.x, wave = t >> 6, lane = t & 63;
    const int quad = lane >> 4, ln = lane & 15;
    const int half = lane >> 5, li = lane & 31;
    const int n0 = blockIdx.x * 16;
    const int nf = n0 + wave * 8;

    // zero own rows in both half-buffers (own-wave rows only)
    {
        float* z0 = &accf[0][wave * 8 * 132];
        float* z1 = &accf[1][wave * 8 * 132];
        for (int i = lane; i < 8 * 132; i += 64) { z0[i] = 0.f; z1[i] = 0.f; }
    }

    if (nf < NN) {
        const int nl = min(nf + 8, NN);
        const int ebeg = __builtin_amdgcn_readfirstlane(rp[nf]);
        const int eend = __builtin_amdgcn_readfirstlane(rp[nl]);
        if (ebeg < eend) {
            float4 racc = make_float4(0.f, 0.f, 0.f, 0.f);
            int curd = (int)((ew[min(ebeg + half, eend - 1)].x >> 16) & 15u);
            const unsigned char* Xl = X8 + li * 4;
            uint2 rec[8], recN[8]; unsigned g[8];
#pragma unroll
            for (int j = 0; j < 8; ++j) rec[j]  = ew[ebeg + 2 * j + half];        // pad-safe
#pragma unroll
            for (int j = 0; j < 8; ++j) recN[j] = ew[ebeg + 16 + 2 * j + half];   // pad-safe
#pragma unroll
            for (int j = 0; j < 8; ++j) {
                int src = (int)(rec[j].x & 0xFFFFu);
                g[j] = *(const unsigned*)(Xl + (size_t)src * 128);
            }
            for (int e = ebeg; e < eend; e += 16) {
                // issue next round's gathers + round-after-next records
                unsigned gN[8]; uint2 recNN[8];
#pragma unroll
                for (int j = 0; j < 8; ++j) {
                    int src = (int)(recN[j].x & 0xFFFFu);
                    gN[j] = *(const unsigned*)(Xl + (size_t)src * 128);
                }
#pragma unroll
                for (int j = 0; j < 8; ++j) recNN[j] = ew[e + 32 + 2 * j + half]; // pad-safe
                // consume current round (waits only on g)
                int lim = eend - e;
                int mj = lim > half ? ((lim - half + 1) >> 1) : 0; if (mj > 8) mj = 8;
#pragma unroll
                for (int j = 0; j < 8; ++j) {
                    if (j >= mj) break;                  // half-uniform (tail only)
                    float wgt = __uint_as_float(rec[j].y);
                    int dl = (int)((rec[j].x >> 16) & 15u);
                    if (dl != curd) {                    // half-uniform, 1 store
                        *(float4*)&accf[half][curd * 132 + li * 4] = racc;
                        racc = make_float4(0.f, 0.f, 0.f, 0.f);
                        curd = dl;
                    }
                    float2 p0 = d2fp8((unsigned short)(g[j] & 0xFFFFu));
                    float2 p1 = d2fp8((unsigned short)(g[j] >> 16));
                    racc.x = fmaf(wgt, p0.x, racc.x);
                    racc.y = fmaf(wgt, p0.y, racc.y);
                    racc.z = fmaf(wgt, p1.x, racc.z);
                    racc.w = fmaf(wgt, p1.y, racc.w);
                }
#pragma unroll
                for (int j = 0; j < 8; ++j) { rec[j] = recN[j]; recN[j] = recNN[j]; g[j] = gN[j]; }
            }
            *(float4*)&accf[half][curd * 132 + li * 4] = racc;   // final flush
        }
    }
    __syncthreads();

    // MFMA phase (redundant across the 2 waves): A = accf[0]+accf[1], B from L2
    f32x4 acc[8] = {};
    const float* ar0 = &accf[0][(size_t)ln * 132];
    const float* ar1 = &accf[1][(size_t)ln * 132];
#pragma unroll
    for (int c = 0; c < 4; ++c) {
        float4 a0 = *(const float4*)(ar0 + c * 32 + quad * 8);
        float4 a1 = *(const float4*)(ar0 + c * 32 + quad * 8 + 4);
        float4 b0 = *(const float4*)(ar1 + c * 32 + quad * 8);
        float4 b1 = *(const float4*)(ar1 + c * 32 + quad * 8 + 4);
        short8 af;
        af[0] = (short)f2bf(a0.x + b0.x); af[1] = (short)f2bf(a0.y + b0.y);
        af[2] = (short)f2bf(a0.z + b0.z); af[3] = (short)f2bf(a0.w + b0.w);
        af[4] = (short)f2bf(a1.x + b1.x); af[5] = (short)f2bf(a1.y + b1.y);
        af[6] = (short)f2bf(a1.z + b1.z); af[7] = (short)f2bf(a1.w + b1.w);
#pragma unroll
        for (int b = 0; b < 8; ++b) {
            short8 bb = *(const short8*)(Wp + ((size_t)(c * 8 + b) * 64 + lane) * 8);
            acc[b] = __builtin_amdgcn_mfma_f32_16x16x32_bf16(af, bb, acc[b], 0, 0, 0);
        }
    }

    float b_s[8], g_s[8], e_s[8];
#pragma unroll
    for (int b = 0; b < 8; ++b) {
        int col = b * 16 + ln;
        b_s[b] = bias[col]; g_s[b] = lng[col]; e_s[b] = lnb[col];
    }
#pragma unroll
    for (int i = 0; i < 4; ++i) {
        int row = n0 + quad * 4 + i;
        float v[8]; float s = 0.f, q = 0.f;
#pragma unroll
        for (int b = 0; b < 8; ++b) { float x = acc[b][i] + b_s[b]; v[b] = x; s += x; q += x * x; }
#pragma unroll
        for (int o = 1; o < 16; o <<= 1) { s += __shfl_xor(s, o, 64); q += __shfl_xor(q, o, 64); }
        float m  = s * (1.0f / 128.0f);
        float vr = q * (1.0f / 128.0f) - m * m;
        float rs = rsqrtf(vr + 1e-5f);
        if (((quad >> 1) == wave) && row < NN) {   // each wave stores its half
#pragma unroll
            for (int b = 0; b < 8; ++b) {
                float o2 = (v[b] - m) * rs * g_s[b] + e_s[b];
                out[(size_t)row * 128 + b * 16 + ln] = f2bf(o2);
                if (out8) out8[(size_t)row * 128 + b * 16 + ln] = e2fp8(o2);
            }
        }
    }
}

// ---------- MFMA gate (LDS-staged W), writes bf16 + fp8 shadow ----------
__global__ __launch_bounds__(256) void k_gate_mfma(
    unsigned short* __restrict__ cur, const unsigned short* __restrict__ hnew,
    const unsigned short* __restrict__ Wp, const float* __restrict__ gb,
    unsigned char* __restrict__ cur8)
{
    __shared__ unsigned short Ws[16384];
    const int t = threadIdx.x;
    const int wave = t >> 6, lane = t & 63;
    const int quad = lane >> 4, ln = lane & 15;
    const int r0 = blockIdx.x * 64 + wave * 16;
    const int arow = r0 + ln;
    const bool av = arow < NN;

    f32x4 acc[8] = {};
#pragma unroll
    for (int s = 0; s < 2; ++s) {
        __syncthreads();
        {
            const float4* src = (const float4*)(Wp + (size_t)s * 16384);
            float4* dst = (float4*)Ws;
#pragma unroll
            for (int i = 0; i < 8; ++i) dst[t + i * 256] = src[t + i * 256];
        }
        __syncthreads();
        const unsigned short* A = s ? hnew : cur;
#pragma unroll
        for (int c = 0; c < 4; ++c) {
            short8 a = {};
            if (av) a = *(const short8*)(A + (size_t)arow * 128 + c * 32 + quad * 8);
#pragma unroll
            for (int b = 0; b < 8; ++b) {
                short8 bb = *(const short8*)&Ws[((c * 8 + b) * 64 + lane) * 8];
                acc[b] = __builtin_amdgcn_mfma_f32_16x16x32_bf16(a, bb, acc[b], 0, 0, 0);
            }
        }
    }

    float gb_s[8];
#pragma unroll
    for (int b = 0; b < 8; ++b) gb_s[b] = gb[b * 16 + ln];
#pragma unroll
    for (int i = 0; i < 4; ++i) {
        int row = r0 + quad * 4 + i;
        if (row < NN) {
#pragma unroll
            for (int b = 0; b < 8; ++b) {
                size_t idx = (size_t)row * 128 + b * 16 + ln;
                float g  = sigm(acc[b][i] + gb_s[b]);
                float cu = bf2f(cur[idx]);
                float hn = bf2f(hnew[idx]);
                float r  = g * hn + (1.f - g) * cu;
                cur[idx]  = f2bf(r);
                cur8[idx] = e2fp8(r);
            }
        }
    }
}

// ---------- RK4 stage combine (bf16 state, fp32 accumulator, fp8 shadow of y) ----------
template<int S>
__global__ __launch_bounds__(256) void k_stage(
    const unsigned short* __restrict__ cur, const unsigned short* __restrict__ fin,
    const unsigned short* __restrict__ h0, float* __restrict__ acc,
    unsigned short* __restrict__ ybuf, const float* __restrict__ scal,
    const float* __restrict__ rwp, unsigned char* __restrict__ y8)
{
    size_t i = (size_t)blockIdx.x * 256 + threadIdx.x;
    if (i >= (size_t)NN * 32) return;
    float dt = scal[1], rw = rwp[0];
    float wk = (S == 1 || S == 4) ? dt * (1.f / 6.f) : dt * (1.f / 3.f);
    ushort4 c4 = ((const ushort4*)cur)[i];
    ushort4 f4 = ((const ushort4*)fin)[i];
    ushort4 h4 = ((const ushort4*)h0)[i];
    float tv[4];
    tv[0] = tanhf(bf2f(c4.x)) + rw * bf2f(f4.x);
    tv[1] = tanhf(bf2f(c4.y)) + rw * bf2f(f4.y);
    tv[2] = tanhf(bf2f(c4.z)) + rw * bf2f(f4.z);
    tv[3] = tanhf(bf2f(c4.w)) + rw * bf2f(f4.w);
    float4 a;
    if (S == 1) { a.x = wk*tv[0]; a.y = wk*tv[1]; a.z = wk*tv[2]; a.w = wk*tv[3]; }
    else {
        a = ((const float4*)acc)[i];
        a.x += wk*tv[0]; a.y += wk*tv[1]; a.z += wk*tv[2]; a.w += wk*tv[3];
    }
    ((float4*)acc)[i] = a;
    float h[4] = { bf2f(h4.x), bf2f(h4.y), bf2f(h4.z), bf2f(h4.w) };
    float yv[4];
    if (S == 4) {
        yv[0] = h[0] + a.x; yv[1] = h[1] + a.y; yv[2] = h[2] + a.z; yv[3] = h[3] + a.w;
    } else {
        float cn = (S == 3) ? dt : 0.5f * dt;
        yv[0] = h[0] + cn*tv[0]; yv[1] = h[1] + cn*tv[1];
        yv[2] = h[2] + cn*tv[2]; yv[3] = h[3] + cn*tv[3];
    }
    ushort4 y;
    y.x = f2bf(yv[0]); y.y = f2bf(yv[1]); y.z = f2bf(yv[2]); y.w = f2bf(yv[3]);
    ((ushort4*)ybuf)[i] = y;
    ((unsigned*)y8)[i] = pk4fp8(yv[0], yv[1], yv[2], yv[3]);
}

// ---------- pooling, two-phase (pool1 writes all 8 groups -> no memset needed) ----------
__global__ __launch_bounds__(128) void k_pool1(
    const unsigned short* __restrict__ h, const int* __restrict__ batch,
    float* __restrict__ partial)
{
    int c = threadIdx.x, b = blockIdx.x;
    int r0 = b * (NN / PB), r1 = r0 + (NN / PB);
    float acc = 0.f;
    int gfirst = batch[r0], g = gfirst;
#pragma unroll 4
    for (int r = r0; r < r1; ++r) {
        int gg = batch[r];
        if (gg != g) {
            partial[(size_t)b * 1024 + g * 128 + c] = acc;
            for (int z = g + 1; z < gg; ++z) partial[(size_t)b * 1024 + z * 128 + c] = 0.f;
            acc = 0.f; g = gg;
        }
        acc += bf2f(h[(size_t)r * 128 + c]);
    }
    partial[(size_t)b * 1024 + g * 128 + c] = acc;
    for (int z = 0; z < gfirst; ++z)  partial[(size_t)b * 1024 + z * 128 + c] = 0.f;
    for (int z = g + 1; z < GG; ++z)  partial[(size_t)b * 1024 + z * 128 + c] = 0.f;
}

__global__ __launch_bounds__(256) void k_pool2(
    const float* __restrict__ partial, const int* __restrict__ st,
    float* __restrict__ out)
{
    __shared__ float sh[8][32];
    int cb = blockIdx.x & 3, g = blockIdx.x >> 2;
    int cl = threadIdx.x & 31, sl = threadIdx.x >> 5;
    int c = cb * 32 + cl;
    float s = 0.f;
    for (int b = sl; b < PB; b += 8) s += partial[(size_t)b * 1024 + g * 128 + c];
    sh[sl][cl] = s; __syncthreads();
    if (sl == 0) {
        float tt = 0.f;
#pragma unroll
        for (int i = 0; i < 8; ++i) tt += sh[i][cl];
        int cnt = st[g + 1] - st[g];
        out[g * 128 + c] = tt / (float)(cnt > 0 ? cnt : 1);
    }
}

// ---------- host ----------
static inline size_t al(size_t x) { return (x + 255) & ~(size_t)255; }

extern "C" void kernel_launch(void* const* d_in, const int* in_sizes, int n_in,
                              void* d_out, int out_size, void* d_ws, size_t ws_size,
                              hipStream_t stream)
{
    const float* x       = (const float*)d_in[0];
    const int*   ei      = (const int*)d_in[1];
    const int*   batch   = (const int*)d_in[2];
    const float* in_w    = (const float*)d_in[3];
    const float* in_b    = (const float*)d_in[4];
    const float* in_lng  = (const float*)d_in[5];
    const float* in_lnb  = (const float*)d_in[6];
    const float* meth    = (const float*)d_in[7];
    const float* histn   = (const float*)d_in[8];
    const float* logd    = (const float*)d_in[9];
    const float* gcn_w   = (const float*)d_in[10];
    const float* gcn_b   = (const float*)d_in[11];
    const float* ln_g    = (const float*)d_in[12];
    const float* ln_b    = (const float*)d_in[13];
    const float* gate_w  = (const float*)d_in[14];
    const float* gate_b  = (const float*)d_in[15];
    const float* rw      = (const float*)d_in[16];
    const float* out_w   = (const float*)d_in[17];
    const float* out_b   = (const float*)d_in[18];
    const float* out_lng = (const float*)d_in[19];
    const float* out_lnb = (const float*)d_in[20];
    float* out = (float*)d_out;

    char* w = (char*)d_ws;
    size_t off = 0;
    float* scal   = (float*)(w + off); off += al(16 * 4);
    int*   hist   = (int*)(w + off);   off += al((size_t)NN * 4);
    int*   rp     = (int*)(w + off);   off += al((size_t)(NN + 1) * 4);
    int*   cursor = (int*)(w + off);   off += al((size_t)(NN + 1) * 4);
    int*   aux    = (int*)(w + off);   off += al(64 * 4);
    int*   st     = (int*)(w + off);   off += al(16 * 4);
    float* dinv   = (float*)(w + off); off += al((size_t)NN * 4);
    uint2* ew     = (uint2*)(w + off); off += al((size_t)(EE + 128) * 8);
    float* partial= (float*)(w + off); off += al((size_t)PB * 1024 * 4);
    // packed bf16 weights: [in | gcn0 | gcn1 | gcn2 | gate0 | gate1 | out] contiguous
    unsigned short* wpak = (unsigned short*)(w + off); off += al((size_t)(8192 + 6 * 16384) * 2);
    unsigned short* inwp  = wpak;
    unsigned short* gcnwp = wpak + 8192;
    unsigned short* gwp   = wpak + 8192 + 3 * 16384;
    unsigned short* owp   = wpak + 8192 + 5 * 16384;
    // bf16 activations
    size_t B16 = al((size_t)NN * 128 * 2);
    unsigned short* xb  = (unsigned short*)(w + off); off += al((size_t)NN * 64 * 2);
    unsigned short* h0  = (unsigned short*)(w + off); off += B16;
    unsigned short* y   = (unsigned short*)(w + off); off += B16;
    unsigned short* cur = (unsigned short*)(w + off); off += B16;
    unsigned short* t2  = (unsigned short*)(w + off); off += B16;
    float* acc = (float*)(w + off); off += al((size_t)NN * 128 * 4);
    // fp8 gather shadows
    size_t B8 = al((size_t)NN * 128);
    unsigned char* h08  = (unsigned char*)(w + off); off += B8;
    unsigned char* y8   = (unsigned char*)(w + off); off += B8;
    unsigned char* cur8 = (unsigned char*)(w + off); off += B8;
    if (off > ws_size) return;

    hipMemsetAsync(hist, 0, (size_t)NN * 4, stream);

    // setup+bounds, merged pack, x conversion (independent)
    k_setup<<<2, 64, 0, stream>>>(meth, histn, logd, scal, batch, st);
    k_packall<<<(8192 + 6 * 16384 + 255) / 256, 256, 0, stream>>>(in_w, gcn_w, gate_w, out_w, wpak);
    k_cvtx<<<3125, 256, 0, stream>>>(x, xb);

    // CSR build
    k_hist<<<(EE + 255) / 256, 256, 0, stream>>>(ei, hist);
    k_dinv<<<(NN + 255) / 256, 256, 0, stream>>>(hist, dinv);
    k_scan_a<<<49, 256, 0, stream>>>(hist, aux);
    k_scan_b<<<1, 1, 0, stream>>>(aux, 49);
    k_scan_c<<<49, 256, 0, stream>>>(hist, aux, rp);
    hipMemcpyAsync(cursor, rp, (size_t)(NN + 1) * 4, hipMemcpyDeviceToDevice, stream);
    k_scatter<<<SB, 256, 0, stream>>>(ei, dinv, cursor, ew);

    const int DG = (NN + 63) / 64;     // 782 blocks (dense/gate)
    const int SG = (NN + 15) / 16;     // 3125 blocks (spgemm)
    k_dense_mfma<2, 1><<<DG, 256, 0, stream>>>(xb, inwp, in_b, in_lng, in_lnb, scal, h0, h08);

    for (int s = 1; s <= 4; ++s) {
        const unsigned short* fin = (s == 1) ? h0 : y;
        const unsigned char*  fin8 = (s == 1) ? h08 : y8;
        k_spgemm<<<SG, 128, 0, stream>>>(rp, ew, fin8, gcnwp, gcn_b, ln_g, ln_b, cur, cur8);
        for (int i = 1; i <= 2; ++i) {
            k_spgemm<<<SG, 128, 0, stream>>>(rp, ew, cur8,
                                             gcnwp + (size_t)i * 128 * 128, gcn_b + i * 128,
                                             ln_g + i * 128, ln_b + i * 128, t2, (unsigned char*)0);
            k_gate_mfma<<<DG, 256, 0, stream>>>(cur, t2, gwp, gate_b, cur8);
        }
        if (s == 1)      k_stage<1><<<6250, 256, 0, stream>>>(cur, fin, h0, acc, y, scal, rw, y8);
        else if (s == 2) k_stage<2><<<6250, 256, 0, stream>>>(cur, fin, h0, acc, y, scal, rw, y8);
        else if (s == 3) k_stage<3><<<6250, 256, 0, stream>>>(cur, fin, h0, acc, y, scal, rw, y8);
        else             k_stage<4><<<6250, 256, 0, stream>>>(cur, fin, h0, acc, y, scal, rw, y8);
    }

    // output projection + pool
    k_dense_mfma<4, 0><<<DG, 256, 0, stream>>>(y, owp, out_b, out_lng, out_lnb, scal, t2, (unsigned char*)0);
    k_pool1<<<PB, 128, 0, stream>>>(t2, batch, partial);
    k_pool2<<<GG * 4, 256, 0, stream>>>(partial, st, out);
}